// Round 1
// baseline (1407.839 us; speedup 1.0000x reference)
//
#include <hip/hip_runtime.h>
#include <stdint.h>

// Decoder_75935021793458: B=256,S=64,N=64,E=128,H=128
// One 256-thread block per batch row b; 64 sequential steps inside.
// Outputs (flat f32): hlp[256] | llp[256] | hr[256] | lr[256] | hact[256*64] | lact[256*64]

#define NB 256
#define NS 64
#define NN 64
#define NE 128
#define NH 128

// ---- Threefry-2x32 (matches jax._src.prng.threefry2x32) ----
__device__ __forceinline__ void tf2x32(uint32_t k0, uint32_t k1,
                                       uint32_t x0, uint32_t x1,
                                       uint32_t &o0, uint32_t &o1) {
  const uint32_t R[5][4] = {{13,15,26,6},{17,29,16,24},{13,15,26,6},{17,29,16,24},{13,15,26,6}};
  uint32_t ks[3] = {k0, k1, k0 ^ k1 ^ 0x1BD11BDAu};
  x0 += ks[0]; x1 += ks[1];
  #pragma unroll
  for (int g = 0; g < 5; ++g) {
    #pragma unroll
    for (int r = 0; r < 4; ++r) {
      x0 += x1;
      uint32_t d = R[g][r];
      x1 = (x1 << d) | (x1 >> (32 - d));
      x1 ^= x0;
    }
    x0 += ks[(g + 1) % 3];
    x1 += ks[(g + 2) % 3] + (uint32_t)(g + 1);
  }
  o0 = x0; o1 = x1;
}

// Gumbel noise for step i, flat element e of the (256,64) draw.
// key = fold_in(key(42), i) = threefry((0,42),(0,i)); counts split-halves over n=16384.
__device__ __forceinline__ double gumbel_for(int i, int e) {
  uint32_t fk0, fk1;
  tf2x32(0u, 42u, 0u, (uint32_t)i, fk0, fk1);
  uint32_t a0, a1, x0, x1;
  if (e < 8192) { x0 = (uint32_t)e; x1 = (uint32_t)(e + 8192); }
  else          { x0 = (uint32_t)(e - 8192); x1 = (uint32_t)e; }
  tf2x32(fk0, fk1, x0, x1, a0, a1);
  uint32_t bits = (e < 8192) ? a0 : a1;
  uint32_t fb = (bits >> 9) | 0x3F800000u;
  float f = __uint_as_float(fb) - 1.0f;          // [0,1)
  const float tiny = 1.17549435e-38f;
  float u = f + tiny;                            // f*(1-tiny)+tiny, (1-tiny) rounds to 1
  u = fmaxf(tiny, u);
  return -log(-log((double)u));
}

__global__ __launch_bounds__(256) void decoder_kernel(
    const float* __restrict__ node,   // (B,S,N,E)
    const float* __restrict__ orig,   // (B,S,N,2)
    const float* __restrict__ cellc,  // (B,S,E)
    const int*   __restrict__ hmask,  // (B,S)
    const int*   __restrict__ lmask,  // (B,S,N)
    const float* __restrict__ init_w, // (2E)
    const float* __restrict__ hW,     // (E,E)
    const float* __restrict__ hb,     // (E)
    const float* __restrict__ vwW,    // (2E,E)
    const float* __restrict__ vwb,    // (E)
    const float* __restrict__ Wq,     // (E,H)
    const float* __restrict__ bq,     // (H)
    const float* __restrict__ Wk,     // (E,H)
    const float* __restrict__ bk,     // (H)
    const float* __restrict__ vvec,   // (H)
    const float* __restrict__ vb_p,   // (1)
    const float* __restrict__ wlow,   // (E)
    float* __restrict__ out)
{
  __shared__ float s_vw[NE * NE];        // Wk during init, then vw_W rows 128..255
  __shared__ float s_keys[NS * 130];     // stride 130 kills 16-way bank conflicts in S1
  __shared__ float s_q[NH], s_query[NE], s_hbar[NE], s_base[NE];
  __shared__ float s_v[NH], s_wl[NE], s_bq[NH], s_h[NE], s_cmean[NE];
  __shared__ float s_u[NS], s_pert[NS], s_mask[NS], s_low[NN];
  __shared__ int s_idx;

  const int t = threadIdx.x;
  const int b = blockIdx.x;
  const float vb = vb_p[0];
  const int sI = t >> 2, pI = t & 3;   // 4 threads per s-position / per low-row

  // ---------------- init ----------------
  { // stage Wk -> s_vw
    const float4* src = (const float4*)Wk;
    float4* dst = (float4*)s_vw;
    for (int j = t; j < NE * NH / 4; j += 256) dst[j] = src[j];
  }
  if (t < NH) { s_bq[t] = bq[t]; s_v[t] = vvec[t]; }
  if (t < NE) { s_wl[t] = wlow[t]; }
  if (t < NS) { s_mask[t] = (float)hmask[b * NS + t]; }
  __syncthreads();

  // keys[b] = cell[b] @ Wk + bk  (32 outputs/thread: 8 s-rows x 4 h-cols)
  {
    const int hh0 = (t & 31) * 4;
    const int sb = (t >> 5) * 8;
    float acc[8][4];
    #pragma unroll
    for (int r = 0; r < 8; ++r) { acc[r][0] = acc[r][1] = acc[r][2] = acc[r][3] = 0.f; }
    const float* cb = cellc + (size_t)b * NS * NE;
    #pragma unroll 4
    for (int e = 0; e < NE; ++e) {
      float4 wk = *(const float4*)&s_vw[e * NH + hh0];
      #pragma unroll
      for (int r = 0; r < 8; ++r) {
        float ce = cb[(sb + r) * NE + e];
        acc[r][0] += ce * wk.x; acc[r][1] += ce * wk.y;
        acc[r][2] += ce * wk.z; acc[r][3] += ce * wk.w;
      }
    }
    #pragma unroll
    for (int r = 0; r < 8; ++r)
      #pragma unroll
      for (int c = 0; c < 4; ++c)
        s_keys[(sb + r) * 130 + hh0 + c] = acc[r][c] + bk[hh0 + c];
  }
  __syncthreads();

  { // stage vw_bot (rows 128..255 of vw_W) -> s_vw
    const float4* src = (const float4*)(vwW + NE * NE);
    float4* dst = (float4*)s_vw;
    for (int j = t; j < NE * NE / 4; j += 256) dst[j] = src[j];
  }
  if (t < NE) { // cmean = mean_s cell[b,s,:]
    const float* cb = cellc + (size_t)b * NS * NE;
    double a = 0.0;
    for (int s = 0; s < NS; ++s) a += (double)cb[s * NE + t];
    s_cmean[t] = (float)(a * (1.0 / 64.0));
  }
  __syncthreads();

  if (t < NE) { // h_bar = cmean @ h_W + h_b ; query0 = h_bar + init_w@vw_W + vw_b
    double a = 0.0;
    for (int e = 0; e < NE; ++e) a += (double)s_cmean[e] * (double)hW[e * NE + t];
    float hbar = (float)a + hb[t];
    s_hbar[t] = hbar;
    double iw = 0.0;
    for (int k = 0; k < 2 * NE; ++k) iw += (double)init_w[k] * (double)vwW[k * NE + t];
    s_query[t] = hbar + (float)iw + vwb[t];
  }
  __syncthreads();

  if (t < NH) { // q0 = query0 @ Wq + bq
    double a = 0.0;
    for (int e = 0; e < NE; ++e) a += (double)s_query[e] * (double)Wq[e * NH + t];
    s_q[t] = (float)a + s_bq[t];
  }
  __syncthreads();

  // ---------------- main sequential loop ----------------
  double hlp = 0.0, llp = 0.0, hr = 0.0, lr = 0.0;
  float lnx = 0.f, lny = 0.f;  // last_node, held by thread 0

  for (int i = 0; i < NS; ++i) {
    // S1: u_[s] = 10*tanh( sum_h tanh(q[h]+keys[s][h])*v[h] + vb ) - 1e8*mask[s]
    {
      double part = 0.0;
      #pragma unroll 8
      for (int j = 0; j < 32; ++j) {
        int h = pI + 4 * j;
        float x = s_q[h] + s_keys[sI * 130 + h];
        part += (double)tanhf(x) * (double)s_v[h];
      }
      part += __shfl_xor(part, 1);
      part += __shfl_xor(part, 2);
      if (pI == 0) {
        float uu = (float)part + vb;
        float logit = 10.0f * tanhf(uu) - 1.0e8f * s_mask[sI];
        s_u[sI] = logit;
        double g = gumbel_for(i, b * 64 + sI);
        s_pert[sI] = (float)((double)logit + g);
      }
    }
    __syncthreads();

    // S2: wave 0 — softmax stats + categorical argmax (first-index ties)
    if (t < 64) {
      float logit = s_u[t];
      float pv = s_pert[t];
      float m = logit;
      #pragma unroll
      for (int off = 32; off; off >>= 1) m = fmaxf(m, __shfl_xor(m, off));
      float bv = pv; int bi = t;
      #pragma unroll
      for (int off = 32; off; off >>= 1) {
        float ov = __shfl_xor(bv, off);
        int oi = __shfl_xor(bi, off);
        if (ov > bv || (ov == bv && oi < bi)) { bv = ov; bi = oi; }
      }
      int idx = (i == 0) ? 0 : bi;
      double se = (double)expf(logit - m);
      #pragma unroll
      for (int off = 32; off; off >>= 1) se += __shfl_xor(se, off);
      float li = __shfl(logit, idx);
      if (t == 0) {
        hlp += (double)li - (double)m - log(se);
        s_idx = idx;
        out[4 * NB + b * NS + i] = (float)idx;
      }
      if (t == idx) s_mask[t] = 1.0f;
    }
    __syncthreads();

    const int idx = s_idx;
    // S3a: issue global loads for this idx
    float4 cc[8];
    {
      const float4* np4 = (const float4*)(node + (size_t)(b * NS + idx) * NN * NE);
      #pragma unroll
      for (int j = 0; j < 8; ++j) cc[j] = np4[t * 8 + j];
    }
    if (t < NE) s_h[t] = cellc[(size_t)(b * NS + idx) * NE + t];
    float2 og = make_float2(0.f, 0.f);
    if (t < 64) og = ((const float2*)orig)[(size_t)(b * NS + idx) * NN + t];
    int lm = 0;
    if (pI == 0) lm = lmask[(size_t)(b * NS + idx) * NN + sI];
    __syncthreads();

    // S3b: low logits dot (all threads) + query update (waves 2,3)
    {
      double part = 0.0;
      #pragma unroll
      for (int j = 0; j < 8; ++j) {
        float4 w4 = *(const float4*)&s_wl[pI * 32 + 4 * j];
        part += (double)cc[j].x * w4.x + (double)cc[j].y * w4.y
              + (double)cc[j].z * w4.z + (double)cc[j].w * w4.w;
      }
      part += __shfl_xor(part, 1);
      part += __shfl_xor(part, 2);
      if (pI == 0) s_low[sI] = (float)part - 1.0e8f * (float)lm;
    }
    if (t >= 128) {
      const int e = t - 128;
      if (i == 0) { // base = h_bar + init_h @ vw_top + vw_b (init_h = h at step 0)
        double a = 0.0;
        for (int k = 0; k < NE; ++k) a += (double)s_h[k] * (double)vwW[k * NE + e];
        s_base[e] = s_hbar[e] + (float)a + vwb[e];
      }
      double a = 0.0;
      for (int k = 0; k < NE; ++k) a += (double)s_h[k] * (double)s_vw[k * NE + e];
      s_query[e] = s_base[e] + (float)a;
    }
    __syncthreads();

    // S3c: q = query @ Wq + bq (waves 2,3) || low softmax + rewards (wave 0)
    if (t >= 128) {
      const int hh = t - 128;
      double a = 0.0;
      for (int e = 0; e < NE; ++e) a += (double)s_query[e] * (double)Wq[e * NH + hh];
      s_q[hh] = (float)a + s_bq[hh];
    } else if (t < 64) {
      float ll = s_low[t];
      float m2 = ll;
      #pragma unroll
      for (int off = 32; off; off >>= 1) m2 = fmaxf(m2, __shfl_xor(m2, off));
      double se2 = (double)expf(ll - m2);
      double ssum = (double)ll;
      float bv = ll; int bi = t;
      #pragma unroll
      for (int off = 32; off; off >>= 1) {
        se2 += __shfl_xor(se2, off);
        ssum += __shfl_xor(ssum, off);
        float ov = __shfl_xor(bv, off);
        int oi = __shfl_xor(bi, off);
        if (ov > bv || (ov == bv && oi < bi)) { bv = ov; bi = oi; }
      }
      // rewards from orig rows (lane n holds row n)
      float nx = __shfl(og.x, t + 1), ny = __shfl(og.y, t + 1);
      double d = 0.0;
      if (t < 63) {
        double dx = (double)nx - (double)og.x, dy = (double)ny - (double)og.y;
        d = sqrt(dx * dx + dy * dy);
      }
      #pragma unroll
      for (int off = 32; off; off >>= 1) d += __shfl_xor(d, off);
      float r63x = __shfl(og.x, 63), r63y = __shfl(og.y, 63);
      if (t == 0) {
        llp += ssum - 64.0 * ((double)m2 + log(se2));
        out[4 * NB + NB * NS + b * NS + i] = (float)bi;
        lr += d;
        double cx = (double)lnx - (double)og.x, cy = (double)lny - (double)og.y;
        hr += sqrt(cx * cx + cy * cy);   // last_node vs i_n (row 0, held by lane 0)
        lnx = r63x; lny = r63y;          // last_node <- l_n (row 63)
      }
    }
    __syncthreads();
  }

  if (t == 0) {
    out[b] = (float)hlp;
    out[NB + b] = (float)llp;
    out[2 * NB + b] = (float)hr;
    out[3 * NB + b] = (float)lr;
  }
}

extern "C" void kernel_launch(void* const* d_in, const int* in_sizes, int n_in,
                              void* d_out, int out_size, void* d_ws, size_t ws_size,
                              hipStream_t stream) {
  (void)in_sizes; (void)n_in; (void)d_ws; (void)ws_size; (void)out_size;
  decoder_kernel<<<dim3(NB), dim3(256), 0, stream>>>(
      (const float*)d_in[0],  (const float*)d_in[1],  (const float*)d_in[2],
      (const int*)d_in[3],    (const int*)d_in[4],
      (const float*)d_in[5],  (const float*)d_in[6],  (const float*)d_in[7],
      (const float*)d_in[8],  (const float*)d_in[9],  (const float*)d_in[10],
      (const float*)d_in[11], (const float*)d_in[12], (const float*)d_in[13],
      (const float*)d_in[14], (const float*)d_in[15], (const float*)d_in[16],
      (float*)d_out);
}

// Round 2
// 951.987 us; speedup vs baseline: 1.4788x; 1.4788x over previous
//
#include <hip/hip_runtime.h>
#include <stdint.h>

// Decoder_75935021793458: B=256,S=64,N=64,E=128,H=128
// 3-launch restructure:
//  k_main: per-b prep GEMMs (keys, T=c@Vb, P=T@Wq, c0,q0) + low tables (node streamed once) + gumbel table
//  k_u:    U[b][j][s] = 10*tanh(v . tanh(q_j + keys[s]) + vb) for j in 0..64 (64 = q0/init row)
//  k_loop: 64-step sequential sampling, one wave per row, LDS/shuffle only
// Outputs (flat f32): hlp[256] | llp[256] | hr[256] | lr[256] | hact[256*64] | lact[256*64]

#define NB 256
#define NS 64
#define NN 64
#define NE 128
#define NH 128
#define NEGC 1.0e8f

// ---------------- ws layout (float offsets), total ~26.1 MB ----------------
#define WS_KEYS 0                          // NB*NS*NH
#define WS_P    (WS_KEYS + NB*NS*NH)       // NB*NS*NH
#define WS_C0   (WS_P + NB*NS*NH)          // NB*NH
#define WS_Q0   (WS_C0 + NB*NH)            // NB*NH
#define WS_U    (WS_Q0 + NB*NH)            // NB*65*64
#define WS_GUM  (WS_U + NB*65*64)          // NB*64*64
#define WS_LLP  (WS_GUM + NB*64*64)        // NB*NS
#define WS_LRW  (WS_LLP + NB*NS)           // NB*NS
#define WS_LAC  (WS_LRW + NB*NS)           // NB*NS
#define WS_INX  (WS_LAC + NB*NS)           // NB*NS*2
#define WS_LNX  (WS_INX + NB*NS*2)         // NB*NS*2

// ---- Threefry-2x32 (matches jax._src.prng.threefry2x32) ----
__device__ __forceinline__ void tf2x32(uint32_t k0, uint32_t k1,
                                       uint32_t x0, uint32_t x1,
                                       uint32_t &o0, uint32_t &o1) {
  const uint32_t R[5][4] = {{13,15,26,6},{17,29,16,24},{13,15,26,6},{17,29,16,24},{13,15,26,6}};
  uint32_t ks[3] = {k0, k1, k0 ^ k1 ^ 0x1BD11BDAu};
  x0 += ks[0]; x1 += ks[1];
  #pragma unroll
  for (int g = 0; g < 5; ++g) {
    #pragma unroll
    for (int r = 0; r < 4; ++r) {
      x0 += x1;
      uint32_t d = R[g][r];
      x1 = (x1 << d) | (x1 >> (32 - d));
      x1 ^= x0;
    }
    x0 += ks[(g + 1) % 3];
    x1 += ks[(g + 2) % 3] + (uint32_t)(g + 1);
  }
  o0 = x0; o1 = x1;
}

// Gumbel for flat element e of the (256,64) draw, folded key (fk0,fk1).
// Double-log kept bit-identical to the R0 kernel that passed.
__device__ __forceinline__ float gumbel_from(uint32_t fk0, uint32_t fk1, int e) {
  uint32_t a0, a1, x0, x1;
  if (e < 8192) { x0 = (uint32_t)e; x1 = (uint32_t)(e + 8192); }
  else          { x0 = (uint32_t)(e - 8192); x1 = (uint32_t)e; }
  tf2x32(fk0, fk1, x0, x1, a0, a1);
  uint32_t bits = (e < 8192) ? a0 : a1;
  uint32_t fb = (bits >> 9) | 0x3F800000u;
  float f = __uint_as_float(fb) - 1.0f;
  const float tiny = 1.17549435e-38f;
  float u = fmaxf(tiny, f + tiny);
  return (float)(-log(-log((double)u)));
}

// =======================================================================
__global__ __launch_bounds__(256) void k_main(
    const float* __restrict__ node,   // (B,S,N,E)
    const float* __restrict__ orig,   // (B,S,N,2)
    const float* __restrict__ cellc,  // (B,S,E)
    const int*   __restrict__ lmask,  // (B,S,N)
    const float* __restrict__ init_w, // (2E)
    const float* __restrict__ hW,     // (E,E)
    const float* __restrict__ hb,     // (E)
    const float* __restrict__ vwW,    // (2E,E)
    const float* __restrict__ vwb,    // (E)
    const float* __restrict__ Wq,     // (E,H)
    const float* __restrict__ bq,     // (H)
    const float* __restrict__ Wk,     // (E,H)
    const float* __restrict__ bk,     // (H)
    const float* __restrict__ wlow,   // (E)
    float* __restrict__ ws)
{
  __shared__ float s_t[NS * 132];     // T = cellc[b] @ vw_bot, padded rows
  __shared__ float s_cm[NE], s_hbar[NE], s_base[NE], s_q0e[NE];
  const int t = threadIdx.x;
  const int blk = blockIdx.x;

  if (blk < NB) {
    // ---------------- prep body: one block per b ----------------
    const int b = blk;
    const float* cb = cellc + (size_t)b * NS * NE;
    const int g = t & 31, sg = t >> 5;
    const int hh0 = 4 * g;

    // GEMM1: keys = cb @ Wk + bk  -> ws
    {
      float acc[8][4];
      #pragma unroll
      for (int r = 0; r < 8; ++r) { acc[r][0]=acc[r][1]=acc[r][2]=acc[r][3]=0.f; }
      for (int k = 0; k < NE; k += 4) {
        float4 w0 = *(const float4*)&Wk[(k+0)*NH+hh0];
        float4 w1 = *(const float4*)&Wk[(k+1)*NH+hh0];
        float4 w2 = *(const float4*)&Wk[(k+2)*NH+hh0];
        float4 w3 = *(const float4*)&Wk[(k+3)*NH+hh0];
        #pragma unroll
        for (int r = 0; r < 8; ++r) {
          float4 c4 = *(const float4*)&cb[(sg*8+r)*NE+k];
          acc[r][0] += c4.x*w0.x + c4.y*w1.x + c4.z*w2.x + c4.w*w3.x;
          acc[r][1] += c4.x*w0.y + c4.y*w1.y + c4.z*w2.y + c4.w*w3.y;
          acc[r][2] += c4.x*w0.z + c4.y*w1.z + c4.z*w2.z + c4.w*w3.z;
          acc[r][3] += c4.x*w0.w + c4.y*w1.w + c4.z*w2.w + c4.w*w3.w;
        }
      }
      float4 bb = *(const float4*)&bk[hh0];
      #pragma unroll
      for (int r = 0; r < 8; ++r) {
        float4 o = make_float4(acc[r][0]+bb.x, acc[r][1]+bb.y, acc[r][2]+bb.z, acc[r][3]+bb.w);
        *(float4*)&ws[WS_KEYS + (size_t)b*NS*NH + (sg*8+r)*NH + hh0] = o;
      }
    }
    // GEMM2: T = cb @ vw_bot -> s_t
    {
      const float* Vb = vwW + NE * NE;
      float acc[8][4];
      #pragma unroll
      for (int r = 0; r < 8; ++r) { acc[r][0]=acc[r][1]=acc[r][2]=acc[r][3]=0.f; }
      for (int k = 0; k < NE; k += 4) {
        float4 w0 = *(const float4*)&Vb[(k+0)*NE+hh0];
        float4 w1 = *(const float4*)&Vb[(k+1)*NE+hh0];
        float4 w2 = *(const float4*)&Vb[(k+2)*NE+hh0];
        float4 w3 = *(const float4*)&Vb[(k+3)*NE+hh0];
        #pragma unroll
        for (int r = 0; r < 8; ++r) {
          float4 c4 = *(const float4*)&cb[(sg*8+r)*NE+k];
          acc[r][0] += c4.x*w0.x + c4.y*w1.x + c4.z*w2.x + c4.w*w3.x;
          acc[r][1] += c4.x*w0.y + c4.y*w1.y + c4.z*w2.y + c4.w*w3.y;
          acc[r][2] += c4.x*w0.z + c4.y*w1.z + c4.z*w2.z + c4.w*w3.z;
          acc[r][3] += c4.x*w0.w + c4.y*w1.w + c4.z*w2.w + c4.w*w3.w;
        }
      }
      #pragma unroll
      for (int r = 0; r < 8; ++r)
        *(float4*)&s_t[(sg*8+r)*132 + hh0] =
            make_float4(acc[r][0], acc[r][1], acc[r][2], acc[r][3]);
    }
    if (t < NE) {  // cmean
      float a = 0.f;
      for (int s = 0; s < NS; ++s) a += cb[s*NE+t];
      s_cm[t] = a * (1.0f/64.0f);
    }
    __syncthreads();
    // GEMM3: P = T @ Wq -> ws (no bias; bq lives in c0/q0)
    {
      float acc[8][4];
      #pragma unroll
      for (int r = 0; r < 8; ++r) { acc[r][0]=acc[r][1]=acc[r][2]=acc[r][3]=0.f; }
      for (int k = 0; k < NE; k += 4) {
        float4 w0 = *(const float4*)&Wq[(k+0)*NH+hh0];
        float4 w1 = *(const float4*)&Wq[(k+1)*NH+hh0];
        float4 w2 = *(const float4*)&Wq[(k+2)*NH+hh0];
        float4 w3 = *(const float4*)&Wq[(k+3)*NH+hh0];
        #pragma unroll
        for (int r = 0; r < 8; ++r) {
          float4 c4 = *(const float4*)&s_t[(sg*8+r)*132 + k];
          acc[r][0] += c4.x*w0.x + c4.y*w1.x + c4.z*w2.x + c4.w*w3.x;
          acc[r][1] += c4.x*w0.y + c4.y*w1.y + c4.z*w2.y + c4.w*w3.y;
          acc[r][2] += c4.x*w0.z + c4.y*w1.z + c4.z*w2.z + c4.w*w3.z;
          acc[r][3] += c4.x*w0.w + c4.y*w1.w + c4.z*w2.w + c4.w*w3.w;
        }
      }
      #pragma unroll
      for (int r = 0; r < 8; ++r)
        *(float4*)&ws[WS_P + (size_t)b*NS*NH + (sg*8+r)*NH + hh0] =
            make_float4(acc[r][0], acc[r][1], acc[r][2], acc[r][3]);
    }
    if (t < NE) {  // h_bar = cmean @ h_W + h_b
      float a0=0,a1=0,a2=0,a3=0;
      for (int k = 0; k < NE; k += 4) {
        a0 += s_cm[k+0]*hW[(k+0)*NE+t]; a1 += s_cm[k+1]*hW[(k+1)*NE+t];
        a2 += s_cm[k+2]*hW[(k+2)*NE+t]; a3 += s_cm[k+3]*hW[(k+3)*NE+t];
      }
      s_hbar[t] = (a0+a1)+(a2+a3) + hb[t];
    }
    __syncthreads();
    if (t < NE) {
      // base = h_bar + cellc[b,0] @ vw_top + vw_b   (init_h = cellc[b,0]: idx_0 forced 0)
      float a0=0,a1=0,a2=0,a3=0;
      for (int k = 0; k < NE; k += 4) {
        a0 += cb[k+0]*vwW[(k+0)*NE+t]; a1 += cb[k+1]*vwW[(k+1)*NE+t];
        a2 += cb[k+2]*vwW[(k+2)*NE+t]; a3 += cb[k+3]*vwW[(k+3)*NE+t];
      }
      s_base[t] = s_hbar[t] + (a0+a1)+(a2+a3) + vwb[t];
      // q0e = h_bar + init_w @ vw_W (full 2E) + vw_b
      float e0=0,e1=0,e2=0,e3=0;
      for (int k = 0; k < 2*NE; k += 4) {
        e0 += init_w[k+0]*vwW[(k+0)*NE+t]; e1 += init_w[k+1]*vwW[(k+1)*NE+t];
        e2 += init_w[k+2]*vwW[(k+2)*NE+t]; e3 += init_w[k+3]*vwW[(k+3)*NE+t];
      }
      s_q0e[t] = s_hbar[t] + (e0+e1)+(e2+e3) + vwb[t];
    }
    __syncthreads();
    if (t < NH) {
      float a0=0,a1=0,a2=0,a3=0, b0=0,b1=0,b2=0,b3=0;
      for (int e = 0; e < NE; e += 4) {
        float w0=Wq[(e+0)*NH+t], w1=Wq[(e+1)*NH+t], w2=Wq[(e+2)*NH+t], w3=Wq[(e+3)*NH+t];
        a0 += s_base[e+0]*w0; a1 += s_base[e+1]*w1; a2 += s_base[e+2]*w2; a3 += s_base[e+3]*w3;
        b0 += s_q0e[e+0]*w0;  b1 += s_q0e[e+1]*w1;  b2 += s_q0e[e+2]*w2;  b3 += s_q0e[e+3]*w3;
      }
      ws[WS_C0 + b*NH + t] = (a0+a1)+(a2+a3) + bq[t];
      ws[WS_Q0 + b*NH + t] = (b0+b1)+(b2+b3) + bq[t];
    }
  } else if (blk < NB + 4096) {
    // ---------------- low-table body: 4 (b,s) rows per block, one per wave ----------------
    const int l = blk - NB;
    const int b = l >> 4;
    const int w = t >> 6, lane = t & 63;
    const int s = ((l & 15) << 2) + w;
    const size_t row = (size_t)(b*NS + s)*NN + lane;      // (b,s,n=lane)
    const float4* nr4 = (const float4*)(node + row * (size_t)NE);
    const float4* wl4 = (const float4*)wlow;
    float a0=0,a1=0,a2=0,a3=0;
    #pragma unroll 8
    for (int j = 0; j < 32; j += 4) {
      float4 n0=nr4[j], n1=nr4[j+1], n2=nr4[j+2], n3=nr4[j+3];
      float4 w0=wl4[j], w1=wl4[j+1], w2=wl4[j+2], w3=wl4[j+3];
      a0 += n0.x*w0.x + n0.y*w0.y + n0.z*w0.z + n0.w*w0.w;
      a1 += n1.x*w1.x + n1.y*w1.y + n1.z*w1.z + n1.w*w1.w;
      a2 += n2.x*w2.x + n2.y*w2.y + n2.z*w2.z + n2.w*w2.w;
      a3 += n3.x*w3.x + n3.y*w3.y + n3.z*w3.z + n3.w*w3.w;
    }
    float logit = (a0+a1)+(a2+a3) - NEGC * (float)lmask[row];
    float m2 = logit;
    #pragma unroll
    for (int off = 32; off; off >>= 1) m2 = fmaxf(m2, __shfl_xor(m2, off));
    float se = expf(logit - m2);
    float ss = logit;
    float bv = logit; int bi = lane;
    #pragma unroll
    for (int off = 32; off; off >>= 1) {
      se += __shfl_xor(se, off);
      ss += __shfl_xor(ss, off);
      float ov = __shfl_xor(bv, off); int oi = __shfl_xor(bi, off);
      if (ov > bv || (ov == bv && oi < bi)) { bv = ov; bi = oi; }
    }
    float2 og = ((const float2*)orig)[row];
    float nx = __shfl(og.x, (lane+1)&63), ny = __shfl(og.y, (lane+1)&63);
    float dd = 0.f;
    if (lane < 63) {
      float dx = nx - og.x, dy = ny - og.y;
      dd = sqrtf(dx*dx + dy*dy);
    }
    #pragma unroll
    for (int off = 32; off; off >>= 1) dd += __shfl_xor(dd, off);
    const int o = b*NS + s;
    if (lane == 0) {
      ws[WS_LLP + o] = ss - 64.f*(m2 + logf(se));
      ws[WS_LRW + o] = dd;
      ws[WS_LAC + o] = (float)bi;
      ws[WS_INX + 2*o]   = og.x;
      ws[WS_INX + 2*o+1] = og.y;
    }
    if (lane == 63) {
      ws[WS_LNX + 2*o]   = og.x;
      ws[WS_LNX + 2*o+1] = og.y;
    }
  } else {
    // ---------------- gumbel body ----------------
    const int gblk = blk - NB - 4096;        // 0..1023
    const int i = gblk >> 4;                 // step
    const int b = ((gblk & 15) << 4) + (t >> 4);
    const int s4 = (t & 15) << 2;
    uint32_t fk0, fk1;
    tf2x32(0u, 42u, 0u, (uint32_t)i, fk0, fk1);
    float4 o;
    o.x = gumbel_from(fk0, fk1, b*64 + s4 + 0);
    o.y = gumbel_from(fk0, fk1, b*64 + s4 + 1);
    o.z = gumbel_from(fk0, fk1, b*64 + s4 + 2);
    o.w = gumbel_from(fk0, fk1, b*64 + s4 + 3);
    *(float4*)&ws[WS_GUM + (size_t)b*4096 + i*64 + s4] = o;
  }
}

// =======================================================================
__global__ __launch_bounds__(256) void k_u(const float* __restrict__ vvec,
                                           const float* __restrict__ vb_p,
                                           float* __restrict__ ws)
{
  __shared__ float s_keys[NS * 129];
  __shared__ float s_q[4 * NE];
  __shared__ float s_v[NH];
  const int t = threadIdx.x;
  const int b = blockIdx.x >> 3, rb = blockIdx.x & 7;
  const int nrows = (rb == 7) ? 9 : 8;
  {
    const int s = t >> 2, h0 = (t & 3) * 32;
    const float* src = ws + WS_KEYS + (size_t)b*NS*NH + s*NH + h0;
    #pragma unroll
    for (int j = 0; j < 8; ++j) {
      float4 v4 = *(const float4*)&src[4*j];
      s_keys[s*129 + h0 + 4*j + 0] = v4.x;
      s_keys[s*129 + h0 + 4*j + 1] = v4.y;
      s_keys[s*129 + h0 + 4*j + 2] = v4.z;
      s_keys[s*129 + h0 + 4*j + 3] = v4.w;
    }
  }
  if (t < NH) s_v[t] = vvec[t];
  __syncthreads();
  const float vb = vb_p[0];
  const int w = t >> 6, lane = t & 63;
  for (int r = w; r < nrows; r += 4) {
    const int jj = rb*8 + r;
    {
      const float* c0p = ws + WS_C0 + b*NH;
      const float* q0p = ws + WS_Q0 + b*NH;
      const float* Pp  = ws + WS_P + (size_t)b*NS*NH + (size_t)jj*NH;
      float v1, v2;
      if (jj == 64) { v1 = q0p[lane]; v2 = q0p[lane+64]; }
      else          { v1 = c0p[lane] + Pp[lane]; v2 = c0p[lane+64] + Pp[lane+64]; }
      s_q[w*NE + lane]      = v1;
      s_q[w*NE + lane + 64] = v2;
    }
    float acc = 0.f;
    #pragma unroll 4
    for (int h = 0; h < NH; ++h) {
      float qk = s_q[w*NE + h] + s_keys[lane*129 + h];
      acc += tanhf(qk) * s_v[h];
    }
    ws[WS_U + (size_t)b*4160 + jj*64 + lane] = 10.f * tanhf(acc + vb);
  }
}

// =======================================================================
__global__ __launch_bounds__(64) void k_loop(const int* __restrict__ hmask,
                                             float* __restrict__ out,
                                             const float* __restrict__ ws)
{
  __shared__ float s_U[65 * 64];
  __shared__ float s_gum[64 * 64];
  const int lane = threadIdx.x;
  const int b = blockIdx.x;
  for (int j = lane; j < 65*64; j += 64) s_U[j] = ws[WS_U + (size_t)b*4160 + j];
  for (int j = lane; j < 64*64; j += 64) s_gum[j] = ws[WS_GUM + (size_t)b*4096 + j];
  const int o = b*NS + lane;
  const float lowlp  = ws[WS_LLP + o];
  const float lowrew = ws[WS_LRW + o];
  const float lowact = ws[WS_LAC + o];
  const float inx = ws[WS_INX + 2*o], iny = ws[WS_INX + 2*o+1];
  const float lnx = ws[WS_LNX + 2*o], lny = ws[WS_LNX + 2*o+1];
  float msk = (float)hmask[o];
  float hlp = 0.f, llp = 0.f, hr = 0.f, lr = 0.f;
  float pnx = 0.f, pny = 0.f;
  int prev = 64;   // row 64 of U = q0/init row
  for (int i = 0; i < NS; ++i) {
    float logit = s_U[prev*64 + lane] - NEGC * msk;
    float pert  = logit + s_gum[i*64 + lane];
    float m = logit, bv = pert; int bi = lane;
    #pragma unroll
    for (int off = 32; off; off >>= 1) {
      m = fmaxf(m, __shfl_xor(m, off));
      float ov = __shfl_xor(bv, off); int oi = __shfl_xor(bi, off);
      if (ov > bv || (ov == bv && oi < bi)) { bv = ov; bi = oi; }
    }
    float se = expf(logit - m);
    #pragma unroll
    for (int off = 32; off; off >>= 1) se += __shfl_xor(se, off);
    const int idx = (i == 0) ? 0 : bi;
    float li = __shfl(logit, idx);
    hlp += li - m - logf(se);
    llp += __shfl(lowlp, idx);
    lr  += __shfl(lowrew, idx);
    float ix = __shfl(inx, idx), iy = __shfl(iny, idx);
    float dx = pnx - ix, dy = pny - iy;
    hr += sqrtf(dx*dx + dy*dy);
    pnx = __shfl(lnx, idx); pny = __shfl(lny, idx);
    float lact_v = __shfl(lowact, idx);
    if (lane == 0) {
      out[4*NB + b*NS + i] = (float)idx;
      out[4*NB + NB*NS + b*NS + i] = lact_v;
    }
    if (lane == idx) msk = 1.f;
    prev = idx;
  }
  if (lane == 0) {
    out[b]        = hlp;
    out[NB + b]   = llp;
    out[2*NB + b] = hr;
    out[3*NB + b] = lr;
  }
}

extern "C" void kernel_launch(void* const* d_in, const int* in_sizes, int n_in,
                              void* d_out, int out_size, void* d_ws, size_t ws_size,
                              hipStream_t stream) {
  (void)in_sizes; (void)n_in; (void)out_size; (void)ws_size;
  const float* node   = (const float*)d_in[0];
  const float* orig   = (const float*)d_in[1];
  const float* cellc  = (const float*)d_in[2];
  const int*   hmask  = (const int*)d_in[3];
  const int*   lmask  = (const int*)d_in[4];
  const float* init_w = (const float*)d_in[5];
  const float* hW     = (const float*)d_in[6];
  const float* hb     = (const float*)d_in[7];
  const float* vwW    = (const float*)d_in[8];
  const float* vwb    = (const float*)d_in[9];
  const float* Wq     = (const float*)d_in[10];
  const float* bq     = (const float*)d_in[11];
  const float* Wk     = (const float*)d_in[12];
  const float* bk     = (const float*)d_in[13];
  const float* v      = (const float*)d_in[14];
  const float* vb     = (const float*)d_in[15];
  const float* wlow   = (const float*)d_in[16];
  float* ws  = (float*)d_ws;
  float* out = (float*)d_out;

  k_main<<<dim3(NB + 4096 + 1024), dim3(256), 0, stream>>>(
      node, orig, cellc, lmask, init_w, hW, hb, vwW, vwb,
      Wq, bq, Wk, bk, wlow, ws);
  k_u<<<dim3(2048), dim3(256), 0, stream>>>(v, vb, ws);
  k_loop<<<dim3(NB), dim3(64), 0, stream>>>(hmask, out, ws);
}